// Round 5
// baseline (107.977 us; speedup 1.0000x reference)
//
#include <hip/hip_runtime.h>
#include <math.h>

#define NN 8192
#define DH 64
#define DOUT 10
#define NG 64      // number of graphs
#define NPG 128    // nodes per graph
#define NITER 5
#define CAP 192    // max stored neighbors per row

typedef float f32x4 __attribute__((ext_vector_type(4)));

// Pass 1: one ROW PER WAVE, 4 rows per block of 256. Fully independent waves
// after the one-time sW stage. Scan (nontemporal float4 + ballot + parallel
// prefix-popcount edge extraction) -> per-wave gather -> per-wave linear+ReLU.
__global__ __launch_bounds__(256) void gin1_fused(
    const float* __restrict__ adj, const float* __restrict__ x,
    const float* __restrict__ W, const float* __restrict__ bias,
    float* __restrict__ h, unsigned short* __restrict__ eidx,
    int* __restrict__ counts)
{
    __shared__ float sW[DH * DH];            // 16 KB
    __shared__ float sAcc[4][DH];
    __shared__ unsigned short sIdx[4][CAP];

    for (int t = threadIdx.x; t < DH * DH; t += 256) sW[t] = W[t];
    __syncthreads();                          // sW ready (only barrier)

    const int wave = threadIdx.x >> 6;
    const int lane = threadIdx.x & 63;
    const int row  = (blockIdx.x << 2) + wave;

    const float* arow = adj + (size_t)row * NN;
    const unsigned long long lt = (lane == 63) ? 0x7FFFFFFFFFFFFFFFull
                                               : ((1ull << lane) - 1ull);
    int ec = 0;
    #pragma unroll 4
    for (int j0 = 0; j0 < NN; j0 += 256) {
        f32x4 a4 = __builtin_nontemporal_load(
            reinterpret_cast<const f32x4*>(arow + j0 + lane * 4));
        unsigned long long m0 = __ballot(a4.x != 0.0f);
        unsigned long long m1 = __ballot(a4.y != 0.0f);
        unsigned long long m2 = __ballot(a4.z != 0.0f);
        unsigned long long m3 = __ballot(a4.w != 0.0f);
        int pre = __popcll(m0 & lt) + __popcll(m1 & lt) +
                  __popcll(m2 & lt) + __popcll(m3 & lt);
        int pos = ec + pre;
        int jb = j0 + 4 * lane;
        if ((m0 >> lane) & 1) sIdx[wave][pos++] = (unsigned short)(jb + 0);
        if ((m1 >> lane) & 1) sIdx[wave][pos++] = (unsigned short)(jb + 1);
        if ((m2 >> lane) & 1) sIdx[wave][pos++] = (unsigned short)(jb + 2);
        if ((m3 >> lane) & 1) sIdx[wave][pos++] = (unsigned short)(jb + 3);
        ec += __popcll(m0) + __popcll(m1) + __popcll(m2) + __popcll(m3);
    }

    // edge list -> global (for layer 2)
    for (int e = lane; e < ec; e += 64)
        eidx[(size_t)row * CAP + e] = sIdx[wave][e];
    if (lane == 0) counts[row] = ec;

    // gather: ~82 independent 256B loads, x is L2-resident (2 MB)
    float acc = x[row * DH + lane];            // self-loop
    #pragma unroll 4
    for (int e = 0; e < ec; ++e) {
        int j = sIdx[wave][e];                 // wave-uniform LDS broadcast
        acc += x[j * DH + lane];
    }

    // per-wave 64x64 linear + ReLU (same-wave LDS RAW, no barrier needed)
    sAcc[wave][lane] = acc;
    float o = bias[lane];
    #pragma unroll
    for (int k = 0; k < DH; ++k) o += sAcc[wave][k] * sW[k * DH + lane];
    h[row * DH + lane] = fmaxf(o, 0.0f);
}

// Pass 2: edge-list GIN layer. One wave per row, 4 rows per block.
__global__ __launch_bounds__(256) void gin2_edges(
    const float* __restrict__ x, const unsigned short* __restrict__ eidx,
    const int* __restrict__ counts, const float* __restrict__ W,
    const float* __restrict__ bias, float* __restrict__ out)
{
    __shared__ float sW[DH * DH];
    __shared__ float sAcc[4][DH];
    __shared__ unsigned short sIdx[4][CAP];

    for (int t = threadIdx.x; t < DH * DH; t += 256) sW[t] = W[t];

    const int wave = threadIdx.x >> 6;
    const int lane = threadIdx.x & 63;
    const int row  = (blockIdx.x << 2) + wave;

    const int ec = counts[row];
    for (int e = lane; e < ec; e += 64) sIdx[wave][e] = eidx[(size_t)row * CAP + e];
    __syncthreads();                           // sW + sIdx ready

    float acc = x[row * DH + lane];            // self-loop
    #pragma unroll 4
    for (int e = 0; e < ec; ++e) {
        int j = sIdx[wave][e];
        acc += x[j * DH + lane];
    }

    sAcc[wave][lane] = acc;
    float o = bias[lane];
    #pragma unroll
    for (int k = 0; k < DH; ++k) o += sAcc[wave][k] * sW[k * DH + lane];
    out[row * DH + lane] = fmaxf(o, 0.0f);
}

// One block (256 threads) per graph: power-iteration rs-pool + classifier + log_softmax
__global__ __launch_bounds__(256) void rspool_head(
    const float* __restrict__ h, const float* __restrict__ Wl,
    const float* __restrict__ bl, float* __restrict__ out)
{
    __shared__ float sX[NPG * 65];    // padded LD=65: conflict-free both axes
    __shared__ float sY[NPG];
    __shared__ float sVec[DH];
    __shared__ float sPart[4][DH];
    __shared__ float sPooled[DH];
    __shared__ float sO[DOUT];

    const int g = blockIdx.x;
    const int d = threadIdx.x & 63;
    const int q = threadIdx.x >> 6;

    const float* hg = h + (size_t)g * NPG * DH;
    for (int t = threadIdx.x; t < NPG * DH; t += 256)
        sX[(t >> 6) * 65 + (t & 63)] = hg[t];
    __syncthreads();

    {
        float p = 0.0f;
        for (int i = q * 32; i < q * 32 + 32; ++i) p += sX[i * 65 + d];
        sPart[q][d] = p;
    }
    __syncthreads();
    if (threadIdx.x < 64) {
        float v = sPart[0][d] + sPart[1][d] + sPart[2][d] + sPart[3][d];
        float s = v * v;
        #pragma unroll
        for (int off = 32; off > 0; off >>= 1) s += __shfl_xor(s, off);
        sVec[d] = v / (sqrtf(s) + 1e-8f);
    }
    __syncthreads();

    for (int it = 0; it < NITER; ++it) {
        if (threadIdx.x < NPG) {
            int i = threadIdx.x;
            float yy = 0.0f;
            #pragma unroll
            for (int dd = 0; dd < DH; ++dd) yy += sX[i * 65 + dd] * sVec[dd];
            sY[i] = yy;
        }
        __syncthreads();
        {
            float p = 0.0f;
            for (int i = q * 32; i < q * 32 + 32; ++i) p += sY[i] * sX[i * 65 + d];
            sPart[q][d] = p;
        }
        __syncthreads();
        if (threadIdx.x < 64) {
            float v = sPart[0][d] + sPart[1][d] + sPart[2][d] + sPart[3][d];
            float s = v * v;
            #pragma unroll
            for (int off = 32; off > 0; off >>= 1) s += __shfl_xor(s, off);
            sVec[d] = v / (sqrtf(s) + 1e-8f);
        }
        __syncthreads();
    }

    if (threadIdx.x < NPG) {
        int i = threadIdx.x;
        float yy = 0.0f;
        #pragma unroll
        for (int dd = 0; dd < DH; ++dd) yy += sX[i * 65 + dd] * sVec[dd];
        sY[i] = yy;
    }
    __syncthreads();
    if (threadIdx.x < 64) {
        float s = sY[d] * sY[d] + sY[64 + d] * sY[64 + d];
        #pragma unroll
        for (int off = 32; off > 0; off >>= 1) s += __shfl_xor(s, off);
        float sv = sqrtf(s);
        sPooled[d] = sVec[d] * sv;
    }
    __syncthreads();

    if (threadIdx.x < DOUT) {
        int c = threadIdx.x;
        float o = bl[c];
        #pragma unroll
        for (int dd = 0; dd < DH; ++dd) o += sPooled[dd] * Wl[dd * DOUT + c];
        sO[c] = o;
    }
    __syncthreads();
    if (threadIdx.x < DOUT) {
        int c = threadIdx.x;
        float mx = -INFINITY;
        #pragma unroll
        for (int j = 0; j < DOUT; ++j) mx = fmaxf(mx, sO[j]);
        float se = 0.0f;
        #pragma unroll
        for (int j = 0; j < DOUT; ++j) se += expf(sO[j] - mx);
        out[g * DOUT + c] = sO[c] - mx - logf(se);
    }
}

extern "C" void kernel_launch(void* const* d_in, const int* in_sizes, int n_in,
                              void* d_out, int out_size, void* d_ws, size_t ws_size,
                              hipStream_t stream) {
    const float* x_in = (const float*)d_in[0];
    const float* adj  = (const float*)d_in[1];
    // d_in[2] = idx (graphs are contiguous 128-node blocks by construction)
    const float* W1 = (const float*)d_in[3];
    const float* b1 = (const float*)d_in[4];
    const float* W2 = (const float*)d_in[5];
    const float* b2 = (const float*)d_in[6];
    const float* Wl = (const float*)d_in[7];
    const float* bl = (const float*)d_in[8];
    float* out = (float*)d_out;

    char* ws = (char*)d_ws;
    float* h1 = (float*)ws;                                   // 2 MB
    float* h2 = h1 + NN * DH;                                 // 2 MB
    int*   counts = (int*)(ws + 4 * 1024 * 1024);             // 32 KB
    unsigned short* eidx = (unsigned short*)(ws + 5 * 1024 * 1024);  // 3.1 MB

    gin1_fused<<<NN / 4, 256, 0, stream>>>(adj, x_in, W1, b1, h1, eidx, counts);
    gin2_edges<<<NN / 4, 256, 0, stream>>>(h1, eidx, counts, W2, b2, h2);
    rspool_head<<<NG, 256, 0, stream>>>(h2, Wl, bl, out);
}

// Round 6
// 103.903 us; speedup vs baseline: 1.0392x; 1.0392x over previous
//
#include <hip/hip_runtime.h>
#include <math.h>

#define NN 8192
#define DH 64
#define DOUT 10
#define NG 64      // number of graphs
#define NPG 128    // nodes per graph
#define NITER 5
#define CAP 192    // max edges per row (deg ~82 +- 9)
#define NCHUNK (NN * NN / 256)   // 262144 chunks of 256 floats
#define RPW 2      // rows per wave in gin_layer

typedef float f32x4 __attribute__((ext_vector_type(4)));
typedef unsigned long long u64;
typedef u64 u64x2 __attribute__((ext_vector_type(2)));

// Grid-stride streaming scan: adj -> occupancy bitmap (32 B per 256-float
// chunk). Mimics the fill kernel's access pattern: all waves march a narrow
// moving window over the 268 MB, maximizing DRAM page locality.
// Bit layout: chunk g, word K (0..3), bit b  <->  column g*256 + 4*b + K.
__global__ __launch_bounds__(256) void scan_bitmap(
    const float* __restrict__ adj, u64* __restrict__ bmp)
{
    const int lane = threadIdx.x & 63;
    const int gw   = (blockIdx.x * 256 + threadIdx.x) >> 6;
    const int nw   = (gridDim.x * 256) >> 6;
    #pragma unroll 4
    for (int g = gw; g < NCHUNK; g += nw) {
        f32x4 a4 = __builtin_nontemporal_load(
            reinterpret_cast<const f32x4*>(adj + (size_t)g * 256 + lane * 4));
        u64 m0 = __ballot(a4.x != 0.0f);
        u64 m1 = __ballot(a4.y != 0.0f);
        u64 m2 = __ballot(a4.z != 0.0f);
        u64 m3 = __ballot(a4.w != 0.0f);
        u64 msel = (lane & 2) ? ((lane & 1) ? m3 : m2)
                              : ((lane & 1) ? m1 : m0);
        if (lane < 4) bmp[(size_t)g * 4 + lane] = msel;
    }
}

// GIN layer from bitmap: one wave per row (RPW rows each).
// Extract edges (popcount + shfl prefix scan) -> gather x -> 64x64 linear
// with W in 64 VGPRs/lane and readlane-broadcast acc. ReLU. No LDS in loop.
__global__ __launch_bounds__(256) void gin_layer(
    const float* __restrict__ x, const u64* __restrict__ bmp,
    const float* __restrict__ W, const float* __restrict__ bias,
    float* __restrict__ out)
{
    __shared__ float sW[DH * DH];
    __shared__ unsigned short sJ[4][CAP];

    for (int t = threadIdx.x; t < DH * DH; t += 256) sW[t] = W[t];
    __syncthreads();

    const int wave = threadIdx.x >> 6;
    const int lane = threadIdx.x & 63;

    float wreg[DH];
    #pragma unroll
    for (int k = 0; k < DH; ++k) wreg[k] = sW[k * DH + lane];  // W column `lane`
    const float bl_ = bias[lane];

    const int wgid = blockIdx.x * 4 + wave;

    for (int rr = 0; rr < RPW; ++rr) {
        const int row = wgid * RPW + rr;
        const u64* brow = bmp + (size_t)row * (NN / 64);   // 128 words

        u64x2 wp = *reinterpret_cast<const u64x2*>(brow + 2 * lane);
        u64 w0 = wp.x, w1 = wp.y;
        int cnt = __popcll(w0) + __popcll(w1);

        int p = cnt;                      // inclusive prefix over lanes
        #pragma unroll
        for (int off = 1; off < 64; off <<= 1) {
            int t = __shfl_up(p, off);
            if (lane >= off) p += t;
        }
        int pos  = p - cnt;               // exclusive prefix
        int ctot = __shfl(p, 63);

        {   // emit edges for my two words (bit b of word widx -> column j)
            int widx = 2 * lane;
            int base0 = (widx >> 2) * 256 + (widx & 3);
            while (w0) { int b = __ffsll(w0) - 1; w0 &= w0 - 1;
                         sJ[wave][pos++] = (unsigned short)(base0 + 4 * b); }
            int widx1 = 2 * lane + 1;
            int base1 = (widx1 >> 2) * 256 + (widx1 & 3);
            while (w1) { int b = __ffsll(w1) - 1; w1 &= w1 - 1;
                         sJ[wave][pos++] = (unsigned short)(base1 + 4 * b); }
        }

        float acc = x[row * DH + lane];   // self-loop
        #pragma unroll 4
        for (int e = 0; e < ctot; ++e) {
            int j = sJ[wave][e];          // wave-uniform LDS broadcast
            acc += x[j * DH + lane];
        }

        float o = bl_;
        #pragma unroll
        for (int k = 0; k < DH; ++k)
            o = fmaf(__shfl(acc, k), wreg[k], o);
        out[row * DH + lane] = fmaxf(o, 0.0f);
    }
}

// One block (256 threads) per graph: power-iteration rs-pool + classifier + log_softmax
__global__ __launch_bounds__(256) void rspool_head(
    const float* __restrict__ h, const float* __restrict__ Wl,
    const float* __restrict__ bl, float* __restrict__ out)
{
    __shared__ float sX[NPG * 65];    // padded LD=65: conflict-free both axes
    __shared__ float sY[NPG];
    __shared__ float sVec[DH];
    __shared__ float sPart[4][DH];
    __shared__ float sPooled[DH];
    __shared__ float sO[DOUT];

    const int g = blockIdx.x;
    const int d = threadIdx.x & 63;
    const int q = threadIdx.x >> 6;

    const float* hg = h + (size_t)g * NPG * DH;
    for (int t = threadIdx.x; t < NPG * DH; t += 256)
        sX[(t >> 6) * 65 + (t & 63)] = hg[t];
    __syncthreads();

    {
        float p = 0.0f;
        for (int i = q * 32; i < q * 32 + 32; ++i) p += sX[i * 65 + d];
        sPart[q][d] = p;
    }
    __syncthreads();
    if (threadIdx.x < 64) {
        float v = sPart[0][d] + sPart[1][d] + sPart[2][d] + sPart[3][d];
        float s = v * v;
        #pragma unroll
        for (int off = 32; off > 0; off >>= 1) s += __shfl_xor(s, off);
        sVec[d] = v / (sqrtf(s) + 1e-8f);
    }
    __syncthreads();

    for (int it = 0; it < NITER; ++it) {
        if (threadIdx.x < NPG) {
            int i = threadIdx.x;
            float yy = 0.0f;
            #pragma unroll
            for (int dd = 0; dd < DH; ++dd) yy += sX[i * 65 + dd] * sVec[dd];
            sY[i] = yy;
        }
        __syncthreads();
        {
            float p = 0.0f;
            for (int i = q * 32; i < q * 32 + 32; ++i) p += sY[i] * sX[i * 65 + d];
            sPart[q][d] = p;
        }
        __syncthreads();
        if (threadIdx.x < 64) {
            float v = sPart[0][d] + sPart[1][d] + sPart[2][d] + sPart[3][d];
            float s = v * v;
            #pragma unroll
            for (int off = 32; off > 0; off >>= 1) s += __shfl_xor(s, off);
            sVec[d] = v / (sqrtf(s) + 1e-8f);
        }
        __syncthreads();
    }

    if (threadIdx.x < NPG) {
        int i = threadIdx.x;
        float yy = 0.0f;
        #pragma unroll
        for (int dd = 0; dd < DH; ++dd) yy += sX[i * 65 + dd] * sVec[dd];
        sY[i] = yy;
    }
    __syncthreads();
    if (threadIdx.x < 64) {
        float s = sY[d] * sY[d] + sY[64 + d] * sY[64 + d];
        #pragma unroll
        for (int off = 32; off > 0; off >>= 1) s += __shfl_xor(s, off);
        float sv = sqrtf(s);
        sPooled[d] = sVec[d] * sv;
    }
    __syncthreads();

    if (threadIdx.x < DOUT) {
        int c = threadIdx.x;
        float o = bl[c];
        #pragma unroll
        for (int dd = 0; dd < DH; ++dd) o += sPooled[dd] * Wl[dd * DOUT + c];
        sO[c] = o;
    }
    __syncthreads();
    if (threadIdx.x < DOUT) {
        int c = threadIdx.x;
        float mx = -INFINITY;
        #pragma unroll
        for (int j = 0; j < DOUT; ++j) mx = fmaxf(mx, sO[j]);
        float se = 0.0f;
        #pragma unroll
        for (int j = 0; j < DOUT; ++j) se += expf(sO[j] - mx);
        out[g * DOUT + c] = sO[c] - mx - logf(se);
    }
}

extern "C" void kernel_launch(void* const* d_in, const int* in_sizes, int n_in,
                              void* d_out, int out_size, void* d_ws, size_t ws_size,
                              hipStream_t stream) {
    const float* x_in = (const float*)d_in[0];
    const float* adj  = (const float*)d_in[1];
    // d_in[2] = idx (graphs are contiguous 128-node blocks by construction)
    const float* W1 = (const float*)d_in[3];
    const float* b1 = (const float*)d_in[4];
    const float* W2 = (const float*)d_in[5];
    const float* b2 = (const float*)d_in[6];
    const float* Wl = (const float*)d_in[7];
    const float* bl = (const float*)d_in[8];
    float* out = (float*)d_out;

    char* ws = (char*)d_ws;
    float* h1 = (float*)ws;                                   // 2 MB
    float* h2 = h1 + NN * DH;                                 // 2 MB
    u64*   bmp = (u64*)(ws + 8 * 1024 * 1024);                // 8 MB bitmap

    scan_bitmap<<<2048, 256, 0, stream>>>(adj, bmp);
    gin_layer<<<NN / (4 * RPW), 256, 0, stream>>>(x_in, bmp, W1, b1, h1);
    gin_layer<<<NN / (4 * RPW), 256, 0, stream>>>(h1, bmp, W2, b2, h2);
    rspool_head<<<NG, 256, 0, stream>>>(h2, Wl, bl, out);
}

// Round 7
// 100.312 us; speedup vs baseline: 1.0764x; 1.0358x over previous
//
#include <hip/hip_runtime.h>
#include <math.h>

#define NN 8192
#define DH 64
#define DOUT 10
#define NG 64      // number of graphs
#define NPG 128    // nodes per graph
#define NITER 5
#define CAP 192    // max edges per row (deg ~82 +- 9)
#define NCHUNK (NN * NN / 256)   // 262144 chunks of 256 floats
#define RPW 2      // rows per wave in gin_layer

typedef float f32x4 __attribute__((ext_vector_type(4)));
typedef unsigned long long u64;
typedef u64 u64x2 __attribute__((ext_vector_type(2)));

// Grid-stride streaming scan: adj -> occupancy bitmap (32 B per 256-float
// chunk). All waves march a narrow moving window over the 268 MB.
// PLAIN loads this round (round 6 used nontemporal — suspected BW killer).
// Bit layout: chunk g, word K (0..3), bit b  <->  column g*256 + 4*b + K.
__global__ __launch_bounds__(256) void scan_bitmap(
    const float* __restrict__ adj, u64* __restrict__ bmp)
{
    const int lane = threadIdx.x & 63;
    const int gw   = (blockIdx.x * 256 + threadIdx.x) >> 6;
    const int nw   = (gridDim.x * 256) >> 6;
    #pragma unroll 4
    for (int g = gw; g < NCHUNK; g += nw) {
        f32x4 a4 = *reinterpret_cast<const f32x4*>(adj + (size_t)g * 256 + lane * 4);
        u64 m0 = __ballot(a4.x != 0.0f);
        u64 m1 = __ballot(a4.y != 0.0f);
        u64 m2 = __ballot(a4.z != 0.0f);
        u64 m3 = __ballot(a4.w != 0.0f);
        u64 msel = (lane & 2) ? ((lane & 1) ? m3 : m2)
                              : ((lane & 1) ? m1 : m0);
        if (lane < 4) bmp[(size_t)g * 4 + lane] = msel;
    }
}

// GIN layer from bitmap: one wave per row (RPW rows each).
// Extract edges (popcount + shfl prefix scan) -> gather x -> 64x64 linear
// with W in 64 VGPRs/lane and readlane-broadcast acc. ReLU. No LDS in loop.
__global__ __launch_bounds__(256) void gin_layer(
    const float* __restrict__ x, const u64* __restrict__ bmp,
    const float* __restrict__ W, const float* __restrict__ bias,
    float* __restrict__ out)
{
    __shared__ float sW[DH * DH];
    __shared__ unsigned short sJ[4][CAP];

    for (int t = threadIdx.x; t < DH * DH; t += 256) sW[t] = W[t];
    __syncthreads();

    const int wave = threadIdx.x >> 6;
    const int lane = threadIdx.x & 63;

    float wreg[DH];
    #pragma unroll
    for (int k = 0; k < DH; ++k) wreg[k] = sW[k * DH + lane];  // W column `lane`
    const float bl_ = bias[lane];

    const int wgid = blockIdx.x * 4 + wave;

    for (int rr = 0; rr < RPW; ++rr) {
        const int row = wgid * RPW + rr;
        const u64* brow = bmp + (size_t)row * (NN / 64);   // 128 words

        u64x2 wp = *reinterpret_cast<const u64x2*>(brow + 2 * lane);
        u64 w0 = wp.x, w1 = wp.y;
        int cnt = __popcll(w0) + __popcll(w1);

        int p = cnt;                      // inclusive prefix over lanes
        #pragma unroll
        for (int off = 1; off < 64; off <<= 1) {
            int t = __shfl_up(p, off);
            if (lane >= off) p += t;
        }
        int pos  = p - cnt;               // exclusive prefix
        int ctot = __shfl(p, 63);

        {   // emit edges for my two words (bit b of word widx -> column j)
            int widx = 2 * lane;
            int base0 = (widx >> 2) * 256 + (widx & 3);
            while (w0) { int b = __ffsll(w0) - 1; w0 &= w0 - 1;
                         sJ[wave][pos++] = (unsigned short)(base0 + 4 * b); }
            int widx1 = 2 * lane + 1;
            int base1 = (widx1 >> 2) * 256 + (widx1 & 3);
            while (w1) { int b = __ffsll(w1) - 1; w1 &= w1 - 1;
                         sJ[wave][pos++] = (unsigned short)(base1 + 4 * b); }
        }

        float acc = x[row * DH + lane];   // self-loop
        #pragma unroll 4
        for (int e = 0; e < ctot; ++e) {
            int j = sJ[wave][e];          // wave-uniform LDS broadcast
            acc += x[j * DH + lane];
        }

        float o = bl_;
        #pragma unroll
        for (int k = 0; k < DH; ++k)
            o = fmaf(__shfl(acc, k), wreg[k], o);
        out[row * DH + lane] = fmaxf(o, 0.0f);
    }
}

// One block (256 threads) per graph: power-iteration rs-pool + classifier + log_softmax
__global__ __launch_bounds__(256) void rspool_head(
    const float* __restrict__ h, const float* __restrict__ Wl,
    const float* __restrict__ bl, float* __restrict__ out)
{
    __shared__ float sX[NPG * 65];    // padded LD=65: conflict-free both axes
    __shared__ float sY[NPG];
    __shared__ float sVec[DH];
    __shared__ float sPart[4][DH];
    __shared__ float sPooled[DH];
    __shared__ float sO[DOUT];

    const int g = blockIdx.x;
    const int d = threadIdx.x & 63;
    const int q = threadIdx.x >> 6;

    const float* hg = h + (size_t)g * NPG * DH;
    for (int t = threadIdx.x; t < NPG * DH; t += 256)
        sX[(t >> 6) * 65 + (t & 63)] = hg[t];
    __syncthreads();

    {
        float p = 0.0f;
        for (int i = q * 32; i < q * 32 + 32; ++i) p += sX[i * 65 + d];
        sPart[q][d] = p;
    }
    __syncthreads();
    if (threadIdx.x < 64) {
        float v = sPart[0][d] + sPart[1][d] + sPart[2][d] + sPart[3][d];
        float s = v * v;
        #pragma unroll
        for (int off = 32; off > 0; off >>= 1) s += __shfl_xor(s, off);
        sVec[d] = v / (sqrtf(s) + 1e-8f);
    }
    __syncthreads();

    for (int it = 0; it < NITER; ++it) {
        if (threadIdx.x < NPG) {
            int i = threadIdx.x;
            float yy = 0.0f;
            #pragma unroll
            for (int dd = 0; dd < DH; ++dd) yy += sX[i * 65 + dd] * sVec[dd];
            sY[i] = yy;
        }
        __syncthreads();
        {
            float p = 0.0f;
            for (int i = q * 32; i < q * 32 + 32; ++i) p += sY[i] * sX[i * 65 + d];
            sPart[q][d] = p;
        }
        __syncthreads();
        if (threadIdx.x < 64) {
            float v = sPart[0][d] + sPart[1][d] + sPart[2][d] + sPart[3][d];
            float s = v * v;
            #pragma unroll
            for (int off = 32; off > 0; off >>= 1) s += __shfl_xor(s, off);
            sVec[d] = v / (sqrtf(s) + 1e-8f);
        }
        __syncthreads();
    }

    if (threadIdx.x < NPG) {
        int i = threadIdx.x;
        float yy = 0.0f;
        #pragma unroll
        for (int dd = 0; dd < DH; ++dd) yy += sX[i * 65 + dd] * sVec[dd];
        sY[i] = yy;
    }
    __syncthreads();
    if (threadIdx.x < 64) {
        float s = sY[d] * sY[d] + sY[64 + d] * sY[64 + d];
        #pragma unroll
        for (int off = 32; off > 0; off >>= 1) s += __shfl_xor(s, off);
        float sv = sqrtf(s);
        sPooled[d] = sVec[d] * sv;
    }
    __syncthreads();

    if (threadIdx.x < DOUT) {
        int c = threadIdx.x;
        float o = bl[c];
        #pragma unroll
        for (int dd = 0; dd < DH; ++dd) o += sPooled[dd] * Wl[dd * DOUT + c];
        sO[c] = o;
    }
    __syncthreads();
    if (threadIdx.x < DOUT) {
        int c = threadIdx.x;
        float mx = -INFINITY;
        #pragma unroll
        for (int j = 0; j < DOUT; ++j) mx = fmaxf(mx, sO[j]);
        float se = 0.0f;
        #pragma unroll
        for (int j = 0; j < DOUT; ++j) se += expf(sO[j] - mx);
        out[g * DOUT + c] = sO[c] - mx - logf(se);
    }
}

extern "C" void kernel_launch(void* const* d_in, const int* in_sizes, int n_in,
                              void* d_out, int out_size, void* d_ws, size_t ws_size,
                              hipStream_t stream) {
    const float* x_in = (const float*)d_in[0];
    const float* adj  = (const float*)d_in[1];
    // d_in[2] = idx (graphs are contiguous 128-node blocks by construction)
    const float* W1 = (const float*)d_in[3];
    const float* b1 = (const float*)d_in[4];
    const float* W2 = (const float*)d_in[5];
    const float* b2 = (const float*)d_in[6];
    const float* Wl = (const float*)d_in[7];
    const float* bl = (const float*)d_in[8];
    float* out = (float*)d_out;

    char* ws = (char*)d_ws;
    float* h1 = (float*)ws;                                   // 2 MB
    float* h2 = h1 + NN * DH;                                 // 2 MB
    u64*   bmp = (u64*)(ws + 8 * 1024 * 1024);                // 8 MB bitmap

    scan_bitmap<<<2048, 256, 0, stream>>>(adj, bmp);
    gin_layer<<<NN / (4 * RPW), 256, 0, stream>>>(x_in, bmp, W1, b1, h1);
    gin_layer<<<NN / (4 * RPW), 256, 0, stream>>>(h1, bmp, W2, b2, h2);
    rspool_head<<<NG, 256, 0, stream>>>(h2, Wl, bl, out);
}